// Round 1
// baseline (14428.484 us; speedup 1.0000x reference)
//
#include <hip/hip_runtime.h>
#include <math.h>

#define NSL 4
#define DM 1024
#define NH 16
#define DKH 64
#define DFF 4096
#define BB 2
#define LL 512      // LS == LT == 512
#define VTOK 32000

// ---------------------------------------------------------------- embedding
__global__ __launch_bounds__(256) void embed_kernel(
    const int* __restrict__ tok, const float* __restrict__ w,
    float* __restrict__ o) {
  const int idx = blockIdx.x * 256 + threadIdx.x;   // over BB*LL*DM = 2^20
  const int dim = idx & (DM - 1);
  const int pos = (idx >> 10) & (LL - 1);
  const int b   = idx >> 19;                         // LL*DM = 2^19
  const int token = tok[b * LL + pos];
  const float denum = powf(10000.0f, (2.0f * (float)dim) / (float)DM);
  const float pe = (float)pos / denum;
  const float val = (dim & 1) ? cosf(pe) : (1.0f + sinf(pe));
  o[idx] = w[(size_t)token * DM + dim] + val;
}

// ---------------------------------------------------------------- GEMM
// C[M,N] = A[M,K] @ W[K,N] + bias[N]  (optional ReLU)
// BM=BN=64, BK=16, 256 threads, 4x4 microtile per thread.
template<int RELU>
__global__ __launch_bounds__(256) void gemm_bias(
    const float* __restrict__ A, const float* __restrict__ W,
    const float* __restrict__ bias, float* __restrict__ C,
    int M, int N, int K) {
  __shared__ float As[16][64 + 1];   // [k][m]
  __shared__ float Bs[16][64 + 1];   // [k][n]
  const int bn = blockIdx.x * 64;
  const int bm = blockIdx.y * 64;
  const int tid = threadIdx.x;
  const int tx = tid & 15, ty = tid >> 4;
  float acc[4][4] = {};
  for (int k0 = 0; k0 < K; k0 += 16) {
    {
      const int m = tid >> 2, kk = (tid & 3) << 2;
      const float4 av = *(const float4*)(A + (size_t)(bm + m) * K + k0 + kk);
      As[kk + 0][m] = av.x; As[kk + 1][m] = av.y;
      As[kk + 2][m] = av.z; As[kk + 3][m] = av.w;
      const int kb = tid >> 4, nb = (tid & 15) << 2;
      const float4 bv = *(const float4*)(W + (size_t)(k0 + kb) * N + bn + nb);
      Bs[kb][nb + 0] = bv.x; Bs[kb][nb + 1] = bv.y;
      Bs[kb][nb + 2] = bv.z; Bs[kb][nb + 3] = bv.w;
    }
    __syncthreads();
    #pragma unroll
    for (int kk = 0; kk < 16; ++kk) {
      float a[4], b[4];
      #pragma unroll
      for (int i = 0; i < 4; ++i) a[i] = As[kk][ty * 4 + i];
      #pragma unroll
      for (int j = 0; j < 4; ++j) b[j] = Bs[kk][tx * 4 + j];
      #pragma unroll
      for (int i = 0; i < 4; ++i)
        #pragma unroll
        for (int j = 0; j < 4; ++j)
          acc[i][j] = fmaf(a[i], b[j], acc[i][j]);
    }
    __syncthreads();
  }
  #pragma unroll
  for (int i = 0; i < 4; ++i) {
    const int row = bm + ty * 4 + i;
    #pragma unroll
    for (int j = 0; j < 4; ++j) {
      const int col = bn + tx * 4 + j;
      float v = acc[i][j] + bias[col];
      if (RELU) v = fmaxf(v, 0.0f);
      C[(size_t)row * N + col] = v;
    }
  }
}

// ---------------------------------------------------------------- attention
__global__ __launch_bounds__(256) void attn_scores(
    const float* __restrict__ q, const float* __restrict__ k,
    float* __restrict__ sc, int causal) {
  const int bh = blockIdx.y;
  const int b = bh >> 4, h = bh & (NH - 1);
  const int idx = blockIdx.x * 256 + threadIdx.x;   // over LL*LL
  const int i = idx >> 9, j = idx & (LL - 1);
  const float4* qp = (const float4*)(q + (size_t)(b * LL + i) * DM + h * DKH);
  const float4* kp = (const float4*)(k + (size_t)(b * LL + j) * DM + h * DKH);
  float acc = 0.0f;
  #pragma unroll
  for (int d = 0; d < DKH / 4; ++d) {
    const float4 a = qp[d], c = kp[d];
    acc += a.x * c.x + a.y * c.y + a.z * c.z + a.w * c.w;
  }
  acc *= 0.125f;   // 1/sqrt(64)
  if (causal && j > i) acc = -INFINITY;
  sc[((size_t)bh * LL + i) * LL + j] = acc;
}

__global__ __launch_bounds__(256) void softmax_rows(float* __restrict__ sc) {
  __shared__ float red[256];
  const int tid = threadIdx.x;
  float* p = sc + (size_t)blockIdx.x * LL;
  const float v0 = p[tid], v1 = p[tid + 256];
  red[tid] = fmaxf(v0, v1);
  __syncthreads();
  for (int s = 128; s > 0; s >>= 1) {
    if (tid < s) red[tid] = fmaxf(red[tid], red[tid + s]);
    __syncthreads();
  }
  const float m = red[0];
  __syncthreads();
  const float e0 = expf(v0 - m), e1 = expf(v1 - m);
  red[tid] = e0 + e1;
  __syncthreads();
  for (int s = 128; s > 0; s >>= 1) {
    if (tid < s) red[tid] += red[tid + s];
    __syncthreads();
  }
  const float inv = 1.0f / red[0];
  p[tid] = e0 * inv;
  p[tid + 256] = e1 * inv;
}

__global__ __launch_bounds__(256) void attn_pv(
    const float* __restrict__ sc, const float* __restrict__ v,
    float* __restrict__ o) {
  const int idx = blockIdx.x * 256 + threadIdx.x;   // over BB*LL*DM
  const int hd = idx & (DM - 1);
  const int bi = idx >> 10;
  const int b = bi >> 9, i = bi & (LL - 1);
  const int h = hd >> 6;
  const float* sp = sc + ((size_t)(b * NH + h) * LL + i) * LL;
  const float* vp = v + (size_t)b * LL * DM + hd;
  float acc = 0.0f;
  for (int j = 0; j < LL; ++j) acc = fmaf(sp[j], vp[(size_t)j * DM], acc);
  o[(size_t)bi * DM + hd] = acc;
}

// ---------------------------------------------------------------- add + LN
__global__ __launch_bounds__(256) void add_ln(
    const float* __restrict__ x, const float* __restrict__ r,
    const float* __restrict__ g, const float* __restrict__ bta,
    float* __restrict__ out) {
  __shared__ float red[256];
  const int tid = threadIdx.x;
  const size_t base = (size_t)blockIdx.x * DM;
  float v[4];
  #pragma unroll
  for (int u = 0; u < 4; ++u) {
    const int c = tid + u * 256;
    v[u] = x[base + c] + r[base + c];
  }
  red[tid] = v[0] + v[1] + v[2] + v[3];
  __syncthreads();
  for (int s = 128; s > 0; s >>= 1) {
    if (tid < s) red[tid] += red[tid + s];
    __syncthreads();
  }
  const float mean = red[0] * (1.0f / DM);
  __syncthreads();
  float sq = 0.0f;
  #pragma unroll
  for (int u = 0; u < 4; ++u) {
    const float dlt = v[u] - mean;
    sq += dlt * dlt;
  }
  red[tid] = sq;
  __syncthreads();
  for (int s = 128; s > 0; s >>= 1) {
    if (tid < s) red[tid] += red[tid + s];
    __syncthreads();
  }
  const float rstd = rsqrtf(red[0] * (1.0f / DM) + 1e-5f);
  #pragma unroll
  for (int u = 0; u < 4; ++u) {
    const int c = tid + u * 256;
    out[base + c] = g[c] * (v[u] - mean) * rstd + bta[c];
  }
}

__global__ __launch_bounds__(256) void addvec(
    const float* __restrict__ a, const float* __restrict__ b,
    float* __restrict__ o) {
  const int i = blockIdx.x * 256 + threadIdx.x;
  o[i] = a[i] + b[i];
}

// ---------------------------------------------------------------- host side
static inline void gemm(hipStream_t st, const float* A, const float* W,
                        const float* bias, float* C, int M, int N, int K,
                        bool relu) {
  dim3 g(N / 64, M / 64);
  if (relu) gemm_bias<1><<<g, 256, 0, st>>>(A, W, bias, C, M, N, K);
  else      gemm_bias<0><<<g, 256, 0, st>>>(A, W, bias, C, M, N, K);
}

static inline void attention(hipStream_t st, const float* q, const float* k,
                             const float* v, float* sc, float* ao, int causal) {
  attn_scores<<<dim3((LL * LL) / 256, BB * NH), 256, 0, st>>>(q, k, sc, causal);
  softmax_rows<<<BB * NH * LL, 256, 0, st>>>(sc);
  attn_pv<<<(BB * LL * DM) / 256, 256, 0, st>>>(sc, v, ao);
}

extern "C" void kernel_launch(void* const* d_in, const int* in_sizes, int n_in,
                              void* d_out, int out_size, void* d_ws, size_t ws_size,
                              hipStream_t stream) {
  (void)in_sizes; (void)n_in; (void)out_size; (void)ws_size;
  const int*   s         = (const int*)d_in[0];
  const int*   t         = (const int*)d_in[1];
  const float* emb_s_w   = (const float*)d_in[2];
  const float* emb_t_w   = (const float*)d_in[3];
  const float* enc_qkv_w = (const float*)d_in[4];
  const float* enc_qkv_b = (const float*)d_in[5];
  const float* enc_o_w   = (const float*)d_in[6];
  const float* enc_o_b   = (const float*)d_in[7];
  const float* enc_ln_w  = (const float*)d_in[8];
  const float* enc_ln_b  = (const float*)d_in[9];
  const float* enc_w1    = (const float*)d_in[10];
  const float* enc_b1    = (const float*)d_in[11];
  const float* enc_w2    = (const float*)d_in[12];
  const float* enc_b2    = (const float*)d_in[13];
  const float* dec_qkv1_w = (const float*)d_in[14];
  const float* dec_qkv1_b = (const float*)d_in[15];
  const float* dec_o1_w   = (const float*)d_in[16];
  const float* dec_o1_b   = (const float*)d_in[17];
  const float* dec_qkv2_w = (const float*)d_in[18];
  const float* dec_qkv2_b = (const float*)d_in[19];
  const float* dec_o2_w   = (const float*)d_in[20];
  const float* dec_o2_b   = (const float*)d_in[21];
  const float* dec_ln_w   = (const float*)d_in[22];
  const float* dec_ln_b   = (const float*)d_in[23];
  const float* dec_w1     = (const float*)d_in[24];
  const float* dec_b1     = (const float*)d_in[25];
  const float* dec_w2     = (const float*)d_in[26];
  const float* dec_b2     = (const float*)d_in[27];
  const float* out_w      = (const float*)d_in[28];
  const float* out_b      = (const float*)d_in[29];
  float* out = (float*)d_out;
  float* ws  = (float*)d_ws;

  const size_t T = (size_t)BB * LL * DM;   // 1,048,576
  float* e    = ws;
  float* dcur = e + T;
  float* qb   = dcur + T;
  float* kb   = qb + T;
  float* vb   = kb + T;
  float* ab   = vb + T;
  float* tmp  = ab + T;
  float* d1b  = tmp + T;
  float* d2b  = d1b + T;
  float* hid  = d2b + T;          // BB*LL*DFF = 4T
  float* sc   = hid + 4 * T;      // BB*NH*LL*LL = 8,388,608

  const int M = BB * LL;          // 1024

  embed_kernel<<<(BB * LL * DM) / 256, 256, 0, stream>>>(s, emb_s_w, e);
  embed_kernel<<<(BB * LL * DM) / 256, 256, 0, stream>>>(t, emb_t_w, dcur);

  // ---- encoder stack ----
  for (int i = 0; i < NSL; ++i) {
    const float* qw = enc_qkv_w + (size_t)i * 3 * DM * DM;
    const float* qv = enc_qkv_b + (size_t)i * 3 * DM;
    gemm(stream, e, qw,                qv,          qb, M, DM, DM, false);
    gemm(stream, e, qw + DM * DM,      qv + DM,     kb, M, DM, DM, false);
    gemm(stream, e, qw + 2 * DM * DM,  qv + 2 * DM, vb, M, DM, DM, false);
    attention(stream, qb, kb, vb, sc, ab, 0);
    gemm(stream, ab, enc_o_w + (size_t)i * DM * DM, enc_o_b + i * DM, tmp, M, DM, DM, false);
    add_ln<<<M, 256, 0, stream>>>(tmp, e, enc_ln_w + i * DM, enc_ln_b + i * DM, e);
    gemm(stream, e, enc_w1 + (size_t)i * DM * DFF, enc_b1 + i * DFF, hid, M, DFF, DM, true);
    gemm(stream, hid, enc_w2 + (size_t)i * DFF * DM, enc_b2 + i * DM, tmp, M, DM, DFF, false);
    add_ln<<<M, 256, 0, stream>>>(tmp, e, enc_ln_w + i * DM, enc_ln_b + i * DM, e);
  }

  // ---- decoder stack ----
  for (int i = 0; i < NSL; ++i) {
    const float* w1p = dec_qkv1_w + (size_t)i * 3 * DM * DM;
    const float* b1p = dec_qkv1_b + (size_t)i * 3 * DM;
    gemm(stream, dcur, w1p,               b1p,          qb, M, DM, DM, false);
    gemm(stream, dcur, w1p + DM * DM,     b1p + DM,     kb, M, DM, DM, false);
    gemm(stream, dcur, w1p + 2 * DM * DM, b1p + 2 * DM, vb, M, DM, DM, false);
    attention(stream, qb, kb, vb, sc, ab, 1);
    gemm(stream, ab, dec_o1_w + (size_t)i * DM * DM, dec_o1_b + i * DM, tmp, M, DM, DM, false);
    add_ln<<<M, 256, 0, stream>>>(tmp, dcur, dec_ln_w + i * DM, dec_ln_b + i * DM, d1b);

    const float* w2p = dec_qkv2_w + (size_t)i * 3 * DM * DM;
    const float* b2p = dec_qkv2_b + (size_t)i * 3 * DM;
    gemm(stream, d1b, w2p,               b2p,          qb, M, DM, DM, false);
    gemm(stream, e,   w2p + DM * DM,     b2p + DM,     kb, M, DM, DM, false);
    gemm(stream, e,   w2p + 2 * DM * DM, b2p + 2 * DM, vb, M, DM, DM, false);
    attention(stream, qb, kb, vb, sc, ab, 1);   // causal in cross-attn too (faithful quirk)
    gemm(stream, ab, dec_o2_w + (size_t)i * DM * DM, dec_o2_b + i * DM, tmp, M, DM, DM, false);
    add_ln<<<M, 256, 0, stream>>>(tmp, d1b, dec_ln_w + i * DM, dec_ln_b + i * DM, d2b);

    gemm(stream, d2b, dec_w1 + (size_t)i * DM * DFF, dec_b1 + i * DFF, hid, M, DFF, DM, true);
    gemm(stream, hid, dec_w2 + (size_t)i * DFF * DM, dec_b2 + i * DM, tmp, M, DM, DFF, false);
    addvec<<<(int)(T / 256), 256, 0, stream>>>(tmp, d2b, dcur);   // no final LN (faithful)
  }

  // ---- output projection ----
  gemm(stream, dcur, out_w, out_b, out, M, VTOK, DM, false);
}

// Round 2
// 2886.177 us; speedup vs baseline: 4.9992x; 4.9992x over previous
//
#include <hip/hip_runtime.h>
#include <hip/hip_bf16.h>
#include <math.h>

#define NSL 4
#define DM 1024
#define NH 16
#define DKH 64
#define DFF 4096
#define BB 2
#define LL 512
#define VTOK 32000

typedef short s16x8 __attribute__((ext_vector_type(8)));
typedef float f32x4 __attribute__((ext_vector_type(4)));

__device__ __forceinline__ void gload16(const void* g, void* l) {
  __builtin_amdgcn_global_load_lds((__attribute__((address_space(1))) void*)g,
                                   (__attribute__((address_space(3))) void*)l, 16, 0, 0);
}

// ---------------------------------------------------------------- embedding (fp32 + bf16 out)
__global__ __launch_bounds__(256) void embed_kernel(
    const int* __restrict__ tok, const float* __restrict__ w,
    float* __restrict__ o, __hip_bfloat16* __restrict__ obf) {
  const int idx = blockIdx.x * 256 + threadIdx.x;   // BB*LL*DM
  const int dim = idx & (DM - 1);
  const int pos = (idx >> 10) & (LL - 1);
  const int b   = idx >> 19;
  const int token = tok[b * LL + pos];
  const float denum = powf(10000.0f, (2.0f * (float)dim) / (float)DM);
  const float pe = (float)pos / denum;
  const float val = (dim & 1) ? cosf(pe) : (1.0f + sinf(pe));
  const float r = w[(size_t)token * DM + dim] + val;
  o[idx] = r;
  obf[idx] = __float2bfloat16(r);
}

// ---------------------------------------------------------------- weight transpose fp32[K][N] -> bf16[N][K]
__global__ __launch_bounds__(256) void transpose_w(
    const float* __restrict__ W, __hip_bfloat16* __restrict__ WT, int K, int N) {
  __shared__ float t[64][65];
  const long mat = blockIdx.z;
  const float* src = W + mat * (long)K * N;
  __hip_bfloat16* dst = WT + mat * (long)N * K;
  const int n0 = blockIdx.x * 64, k0 = blockIdx.y * 64;
  const int tx = threadIdx.x & 63, ty = threadIdx.x >> 6;
  #pragma unroll
  for (int u = 0; u < 16; ++u) {
    const int r = ty * 16 + u;
    t[r][tx] = src[(long)(k0 + r) * N + n0 + tx];
  }
  __syncthreads();
  #pragma unroll
  for (int u = 0; u < 16; ++u) {
    const int r = ty * 16 + u;
    dst[(long)(n0 + r) * K + k0 + tx] = __float2bfloat16(t[tx][r]);
  }
}

// ---------------------------------------------------------------- V transpose bf16 [B*LL][ldv] slice -> VT[B][DM][LL]
__global__ __launch_bounds__(256) void transpose_v(
    const __hip_bfloat16* __restrict__ V, __hip_bfloat16* __restrict__ VT, int ldv) {
  __shared__ __hip_bfloat16 t[64][65];
  const int b = blockIdx.z;
  const int j0 = blockIdx.x * 64, d0 = blockIdx.y * 64;
  const int tx = threadIdx.x & 63, ty = threadIdx.x >> 6;
  const __hip_bfloat16* src = V + (long)b * LL * ldv;
  __hip_bfloat16* dst = VT + (long)b * DM * LL;
  #pragma unroll
  for (int u = 0; u < 16; ++u) {
    const int r = ty * 16 + u;                 // j
    t[r][tx] = src[(long)(j0 + r) * ldv + d0 + tx];
  }
  __syncthreads();
  #pragma unroll
  for (int u = 0; u < 16; ++u) {
    const int r = ty * 16 + u;                 // d
    dst[(long)(d0 + r) * LL + j0 + tx] = t[tx][r];
  }
}

// ---------------------------------------------------------------- MFMA GEMM
// C = alpha * A[M,K] @ BT[N,K]^T (+bias) ; A,BT bf16 k-contiguous; batched via blockIdx.z
// z offsets: off = (z>>4)*sH + (z&15)*sL   (z=0 -> 0)
template<int BN, int RELU, int OBF, int CAUSAL>
__global__ __launch_bounds__(256) void gemm_mfma(
    const __hip_bfloat16* __restrict__ A, const __hip_bfloat16* __restrict__ BT,
    const float* __restrict__ bias, void* __restrict__ Cout,
    int K, int lda, int ldb, int ldc,
    long sAh, long sAl, long sBh, long sBl, long sCh, long sCl, float alpha) {
  constexpr int BM = 128;
  constexpr int BK = 32;
  __shared__ __align__(16) __hip_bfloat16 As[BM * BK];
  __shared__ __align__(16) __hip_bfloat16 Bs[BN * BK];
  const int z = blockIdx.z;
  const __hip_bfloat16* Ab = A + (long)(z >> 4) * sAh + (long)(z & 15) * sAl;
  const __hip_bfloat16* Bb = BT + (long)(z >> 4) * sBh + (long)(z & 15) * sBl;
  const long offC = (long)(z >> 4) * sCh + (long)(z & 15) * sCl;
  const int bm = blockIdx.y * BM;
  const int bn = blockIdx.x * BN;
  const int tid = threadIdx.x;
  const int lane = tid & 63;
  const int wid = tid >> 6;
  constexpr int WGC = (BN == 128) ? 2 : 1;
  constexpr int WR = (BN == 128) ? 64 : 32;     // rows per wave
  constexpr int MF = WR / 16;
  constexpr int NF = 4;                         // 64 cols per wave
  const int wr = (wid / WGC) * WR;
  const int wc = (wid % WGC) * 64;

  f32x4 acc[MF][NF] = {};

  constexpr int ACALLS = BM / 64;               // 2 per wave
  constexpr int BCALLS = BN / 64;               // 2 or 1 per wave
  const int l_row = lane >> 2;
  const int l_chk = lane & 3;
  const int frow = lane & 15;
  const int fkc  = lane >> 4;

  for (int k0 = 0; k0 < K; k0 += BK) {
    #pragma unroll
    for (int c = 0; c < ACALLS; ++c) {
      const int R0 = (wid * ACALLS + c) * 16;
      const int row = R0 + l_row;
      const int chk = l_chk ^ ((row >> 1) & 3);   // pre-swizzled source (rule #21)
      gload16(Ab + (long)(bm + row) * lda + k0 + chk * 8, &As[R0 * BK]);
    }
    #pragma unroll
    for (int c = 0; c < BCALLS; ++c) {
      const int R0 = (wid * BCALLS + c) * 16;
      const int row = R0 + l_row;
      const int chk = l_chk ^ ((row >> 1) & 3);
      gload16(Bb + (long)(bn + row) * ldb + k0 + chk * 8, &Bs[R0 * BK]);
    }
    __syncthreads();
    s16x8 af[MF], bfr[NF];
    #pragma unroll
    for (int m = 0; m < MF; ++m) {
      const int r = wr + m * 16 + frow;
      const int chk = fkc ^ ((r >> 1) & 3);
      af[m] = *(const s16x8*)&As[r * BK + chk * 8];
    }
    #pragma unroll
    for (int n = 0; n < NF; ++n) {
      const int r = wc + n * 16 + frow;
      const int chk = fkc ^ ((r >> 1) & 3);
      bfr[n] = *(const s16x8*)&Bs[r * BK + chk * 8];
    }
    #pragma unroll
    for (int m = 0; m < MF; ++m)
      #pragma unroll
      for (int n = 0; n < NF; ++n)
        acc[m][n] = __builtin_amdgcn_mfma_f32_16x16x32_bf16(af[m], bfr[n], acc[m][n], 0, 0, 0);
    __syncthreads();
  }

  #pragma unroll
  for (int m = 0; m < MF; ++m) {
    #pragma unroll
    for (int n = 0; n < NF; ++n) {
      #pragma unroll
      for (int j = 0; j < 4; ++j) {
        const int row = bm + wr + m * 16 + fkc * 4 + j;
        const int col = bn + wc + n * 16 + frow;
        float v = acc[m][n][j] * alpha;
        if (bias) v += bias[col];
        if (RELU) v = fmaxf(v, 0.0f);
        if (CAUSAL && col > row) v = -1e30f;
        const long ci = offC + (long)row * ldc + col;
        if (OBF) ((__hip_bfloat16*)Cout)[ci] = __float2bfloat16(v);
        else     ((float*)Cout)[ci] = v;
      }
    }
  }
}

// ---------------------------------------------------------------- softmax rows: fp32 sc -> bf16 P
__global__ __launch_bounds__(256) void softmax_rows(
    const float* __restrict__ sc, __hip_bfloat16* __restrict__ P) {
  __shared__ float red[256];
  const int tid = threadIdx.x;
  const float* p = sc + (size_t)blockIdx.x * LL;
  __hip_bfloat16* q = P + (size_t)blockIdx.x * LL;
  const float v0 = p[tid], v1 = p[tid + 256];
  red[tid] = fmaxf(v0, v1);
  __syncthreads();
  for (int s = 128; s > 0; s >>= 1) {
    if (tid < s) red[tid] = fmaxf(red[tid], red[tid + s]);
    __syncthreads();
  }
  const float m = red[0];
  __syncthreads();
  const float e0 = expf(v0 - m), e1 = expf(v1 - m);
  red[tid] = e0 + e1;
  __syncthreads();
  for (int s = 128; s > 0; s >>= 1) {
    if (tid < s) red[tid] += red[tid + s];
    __syncthreads();
  }
  const float inv = 1.0f / red[0];
  q[tid] = __float2bfloat16(e0 * inv);
  q[tid + 256] = __float2bfloat16(e1 * inv);
}

// ---------------------------------------------------------------- add + LN (fp32 + bf16 out)
__global__ __launch_bounds__(256) void add_ln(
    const float* __restrict__ x, const float* __restrict__ r,
    const float* __restrict__ g, const float* __restrict__ bta,
    float* __restrict__ out, __hip_bfloat16* __restrict__ obf) {
  __shared__ float red[256];
  const int tid = threadIdx.x;
  const size_t base = (size_t)blockIdx.x * DM;
  float v[4];
  #pragma unroll
  for (int u = 0; u < 4; ++u) {
    const int c = tid + u * 256;
    v[u] = x[base + c] + r[base + c];
  }
  red[tid] = v[0] + v[1] + v[2] + v[3];
  __syncthreads();
  for (int s = 128; s > 0; s >>= 1) {
    if (tid < s) red[tid] += red[tid + s];
    __syncthreads();
  }
  const float mean = red[0] * (1.0f / DM);
  __syncthreads();
  float sq = 0.0f;
  #pragma unroll
  for (int u = 0; u < 4; ++u) { const float d = v[u] - mean; sq += d * d; }
  red[tid] = sq;
  __syncthreads();
  for (int s = 128; s > 0; s >>= 1) {
    if (tid < s) red[tid] += red[tid + s];
    __syncthreads();
  }
  const float rstd = rsqrtf(red[0] * (1.0f / DM) + 1e-5f);
  #pragma unroll
  for (int u = 0; u < 4; ++u) {
    const int c = tid + u * 256;
    const float o = g[c] * (v[u] - mean) * rstd + bta[c];
    out[base + c] = o;
    obf[base + c] = __float2bfloat16(o);
  }
}

__global__ __launch_bounds__(256) void addvec(
    const float* __restrict__ a, const float* __restrict__ b,
    float* __restrict__ o, __hip_bfloat16* __restrict__ obf) {
  const int i = blockIdx.x * 256 + threadIdx.x;
  const float r = a[i] + b[i];
  o[i] = r;
  obf[i] = __float2bfloat16(r);
}

// ---------------------------------------------------------------- host helpers
template<int BN, int RELU, int OBF, int CAUSAL>
static inline void launch_gemm(hipStream_t st, const __hip_bfloat16* A, const __hip_bfloat16* BT,
                               const float* bias, void* C, int M, int N, int K,
                               int lda, int ldb, int ldc,
                               long sAh, long sAl, long sBh, long sBl, long sCh, long sCl,
                               float alpha, int nz) {
  dim3 g(N / BN, M / 128, nz);
  gemm_mfma<BN, RELU, OBF, CAUSAL><<<g, 256, 0, st>>>(
      A, BT, bias, C, K, lda, ldb, ldc, sAh, sAl, sBh, sBl, sCh, sCl, alpha);
}

static inline void attention(hipStream_t st,
                             const __hip_bfloat16* q, int ldq,
                             const __hip_bfloat16* k, int ldk,
                             const __hip_bfloat16* v, int ldv,
                             float* sc, __hip_bfloat16* P, __hip_bfloat16* VT,
                             __hip_bfloat16* ab, bool causal) {
  transpose_v<<<dim3(LL / 64, DM / 64, BB), 256, 0, st>>>(v, VT, ldv);
  if (causal)
    launch_gemm<128, 0, 0, 1>(st, q, k, nullptr, sc, LL, LL, DKH, ldq, ldk, LL,
                              (long)LL * ldq, 64, (long)LL * ldk, 64,
                              16L * LL * LL, (long)LL * LL, 0.125f, BB * NH);
  else
    launch_gemm<128, 0, 0, 0>(st, q, k, nullptr, sc, LL, LL, DKH, ldq, ldk, LL,
                              (long)LL * ldq, 64, (long)LL * ldk, 64,
                              16L * LL * LL, (long)LL * LL, 0.125f, BB * NH);
  softmax_rows<<<BB * NH * LL, 256, 0, st>>>(sc, P);
  launch_gemm<64, 0, 1, 0>(st, P, VT, nullptr, ab, LL, 64, LL, LL, LL, DM,
                           16L * LL * LL, (long)LL * LL, (long)DM * LL, 64L * LL,
                           (long)LL * DM, 64L, 1.0f, BB * NH);
}

extern "C" void kernel_launch(void* const* d_in, const int* in_sizes, int n_in,
                              void* d_out, int out_size, void* d_ws, size_t ws_size,
                              hipStream_t stream) {
  (void)in_sizes; (void)n_in; (void)out_size; (void)ws_size;
  const int*   s          = (const int*)d_in[0];
  const int*   t          = (const int*)d_in[1];
  const float* emb_s_w    = (const float*)d_in[2];
  const float* emb_t_w    = (const float*)d_in[3];
  const float* enc_qkv_w  = (const float*)d_in[4];
  const float* enc_qkv_b  = (const float*)d_in[5];
  const float* enc_o_w    = (const float*)d_in[6];
  const float* enc_o_b    = (const float*)d_in[7];
  const float* enc_ln_w   = (const float*)d_in[8];
  const float* enc_ln_b   = (const float*)d_in[9];
  const float* enc_w1     = (const float*)d_in[10];
  const float* enc_b1     = (const float*)d_in[11];
  const float* enc_w2     = (const float*)d_in[12];
  const float* enc_b2     = (const float*)d_in[13];
  const float* dec_qkv1_w = (const float*)d_in[14];
  const float* dec_qkv1_b = (const float*)d_in[15];
  const float* dec_o1_w   = (const float*)d_in[16];
  const float* dec_o1_b   = (const float*)d_in[17];
  const float* dec_qkv2_w = (const float*)d_in[18];
  const float* dec_qkv2_b = (const float*)d_in[19];
  const float* dec_o2_w   = (const float*)d_in[20];
  const float* dec_o2_b   = (const float*)d_in[21];
  const float* dec_ln_w   = (const float*)d_in[22];
  const float* dec_ln_b   = (const float*)d_in[23];
  const float* dec_w1     = (const float*)d_in[24];
  const float* dec_b1     = (const float*)d_in[25];
  const float* dec_w2     = (const float*)d_in[26];
  const float* dec_b2     = (const float*)d_in[27];
  const float* out_w      = (const float*)d_in[28];
  const float* out_b      = (const float*)d_in[29];
  float* out = (float*)d_out;

  // ---- workspace carve-up (bytes, 256-aligned) ----
  char* p = (char*)d_ws;
  auto alloc = [&](size_t bytes) {
    char* r = p; p += (bytes + 255) & ~(size_t)255; return (void*)r;
  };
  const size_t T = (size_t)BB * LL * DM;          // 1M elements
  float* e    = (float*)alloc(T * 4);
  float* dcur = (float*)alloc(T * 4);
  float* tmp  = (float*)alloc(T * 4);
  float* d1b  = (float*)alloc(T * 4);
  float* d2b  = (float*)alloc(T * 4);
  float* sc   = (float*)alloc((size_t)BB * NH * LL * LL * 4);
  __hip_bfloat16* e_bf    = (__hip_bfloat16*)alloc(T * 2);
  __hip_bfloat16* dcur_bf = (__hip_bfloat16*)alloc(T * 2);
  __hip_bfloat16* d1b_bf  = (__hip_bfloat16*)alloc(T * 2);
  __hip_bfloat16* d2b_bf  = (__hip_bfloat16*)alloc(T * 2);
  __hip_bfloat16* q_bf    = (__hip_bfloat16*)alloc(T * 2);
  __hip_bfloat16* qkv_bf  = (__hip_bfloat16*)alloc((size_t)BB * LL * 3 * DM * 2);
  __hip_bfloat16* ab_bf   = (__hip_bfloat16*)alloc(T * 2);
  __hip_bfloat16* hid_bf  = (__hip_bfloat16*)alloc((size_t)BB * LL * DFF * 2);
  __hip_bfloat16* P       = (__hip_bfloat16*)alloc((size_t)BB * NH * LL * LL * 2);
  __hip_bfloat16* VT      = (__hip_bfloat16*)alloc((size_t)BB * DM * LL * 2);
  __hip_bfloat16* WT      = (__hip_bfloat16*)alloc((size_t)VTOK * DM * 2);

  const int M = BB * LL;   // 1024

  embed_kernel<<<(int)(T / 256), 256, 0, stream>>>(s, emb_s_w, e, e_bf);
  embed_kernel<<<(int)(T / 256), 256, 0, stream>>>(t, emb_t_w, dcur, dcur_bf);

  // ---- encoder ----
  for (int i = 0; i < NSL; ++i) {
    transpose_w<<<dim3(DM / 64, DM / 64, 3), 256, 0, stream>>>(
        enc_qkv_w + (size_t)i * 3 * DM * DM, WT, DM, DM);
    launch_gemm<128, 0, 1, 0>(stream, e_bf, WT, enc_qkv_b + (size_t)i * 3 * DM, qkv_bf,
                              M, 3 * DM, DM, DM, DM, 3 * DM, 0, 0, 0, 0, 0, 0, 1.0f, 1);
    attention(stream, qkv_bf, 3 * DM, qkv_bf + DM, 3 * DM, qkv_bf + 2 * DM, 3 * DM,
              sc, P, VT, ab_bf, false);
    transpose_w<<<dim3(DM / 64, DM / 64, 1), 256, 0, stream>>>(
        enc_o_w + (size_t)i * DM * DM, WT, DM, DM);
    launch_gemm<128, 0, 0, 0>(stream, ab_bf, WT, enc_o_b + (size_t)i * DM, tmp,
                              M, DM, DM, DM, DM, DM, 0, 0, 0, 0, 0, 0, 1.0f, 1);
    add_ln<<<M, 256, 0, stream>>>(tmp, e, enc_ln_w + (size_t)i * DM, enc_ln_b + (size_t)i * DM, e, e_bf);
    transpose_w<<<dim3(DFF / 64, DM / 64, 1), 256, 0, stream>>>(
        enc_w1 + (size_t)i * DM * DFF, WT, DM, DFF);
    launch_gemm<128, 1, 1, 0>(stream, e_bf, WT, enc_b1 + (size_t)i * DFF, hid_bf,
                              M, DFF, DM, DM, DM, DFF, 0, 0, 0, 0, 0, 0, 1.0f, 1);
    transpose_w<<<dim3(DM / 64, DFF / 64, 1), 256, 0, stream>>>(
        enc_w2 + (size_t)i * DFF * DM, WT, DFF, DM);
    launch_gemm<128, 0, 0, 0>(stream, hid_bf, WT, enc_b2 + (size_t)i * DM, tmp,
                              M, DM, DFF, DFF, DFF, DM, 0, 0, 0, 0, 0, 0, 1.0f, 1);
    add_ln<<<M, 256, 0, stream>>>(tmp, e, enc_ln_w + (size_t)i * DM, enc_ln_b + (size_t)i * DM, e, e_bf);
  }

  // ---- decoder ----
  for (int i = 0; i < NSL; ++i) {
    transpose_w<<<dim3(DM / 64, DM / 64, 3), 256, 0, stream>>>(
        dec_qkv1_w + (size_t)i * 3 * DM * DM, WT, DM, DM);
    launch_gemm<128, 0, 1, 0>(stream, dcur_bf, WT, dec_qkv1_b + (size_t)i * 3 * DM, qkv_bf,
                              M, 3 * DM, DM, DM, DM, 3 * DM, 0, 0, 0, 0, 0, 0, 1.0f, 1);
    attention(stream, qkv_bf, 3 * DM, qkv_bf + DM, 3 * DM, qkv_bf + 2 * DM, 3 * DM,
              sc, P, VT, ab_bf, true);
    transpose_w<<<dim3(DM / 64, DM / 64, 1), 256, 0, stream>>>(
        dec_o1_w + (size_t)i * DM * DM, WT, DM, DM);
    launch_gemm<128, 0, 0, 0>(stream, ab_bf, WT, dec_o1_b + (size_t)i * DM, tmp,
                              M, DM, DM, DM, DM, DM, 0, 0, 0, 0, 0, 0, 1.0f, 1);
    add_ln<<<M, 256, 0, stream>>>(tmp, dcur, dec_ln_w + (size_t)i * DM, dec_ln_b + (size_t)i * DM, d1b, d1b_bf);

    transpose_w<<<dim3(DM / 64, DM / 64, 3), 256, 0, stream>>>(
        dec_qkv2_w + (size_t)i * 3 * DM * DM, WT, DM, DM);
    launch_gemm<128, 0, 1, 0>(stream, d1b_bf, WT, dec_qkv2_b + (size_t)i * 3 * DM, q_bf,
                              M, DM, DM, DM, DM, DM, 0, 0, 0, 0, 0, 0, 1.0f, 1);
    launch_gemm<128, 0, 1, 0>(stream, e_bf, WT + (size_t)DM * DM,
                              dec_qkv2_b + (size_t)i * 3 * DM + DM, qkv_bf,
                              M, 2 * DM, DM, DM, DM, 2 * DM, 0, 0, 0, 0, 0, 0, 1.0f, 1);
    attention(stream, q_bf, DM, qkv_bf, 2 * DM, qkv_bf + DM, 2 * DM,
              sc, P, VT, ab_bf, true);   // causal cross-attn (faithful quirk)
    transpose_w<<<dim3(DM / 64, DM / 64, 1), 256, 0, stream>>>(
        dec_o2_w + (size_t)i * DM * DM, WT, DM, DM);
    launch_gemm<128, 0, 0, 0>(stream, ab_bf, WT, dec_o2_b + (size_t)i * DM, tmp,
                              M, DM, DM, DM, DM, DM, 0, 0, 0, 0, 0, 0, 1.0f, 1);
    add_ln<<<M, 256, 0, stream>>>(tmp, d1b, dec_ln_w + (size_t)i * DM, dec_ln_b + (size_t)i * DM, d2b, d2b_bf);

    transpose_w<<<dim3(DFF / 64, DM / 64, 1), 256, 0, stream>>>(
        dec_w1 + (size_t)i * DM * DFF, WT, DM, DFF);
    launch_gemm<128, 1, 1, 0>(stream, d2b_bf, WT, dec_b1 + (size_t)i * DFF, hid_bf,
                              M, DFF, DM, DM, DM, DFF, 0, 0, 0, 0, 0, 0, 1.0f, 1);
    transpose_w<<<dim3(DM / 64, DFF / 64, 1), 256, 0, stream>>>(
        dec_w2 + (size_t)i * DFF * DM, WT, DFF, DM);
    launch_gemm<128, 0, 0, 0>(stream, hid_bf, WT, dec_b2 + (size_t)i * DM, tmp,
                              M, DM, DFF, DFF, DFF, DM, 0, 0, 0, 0, 0, 0, 1.0f, 1);
    addvec<<<(int)(T / 256), 256, 0, stream>>>(tmp, d2b, dcur, dcur_bf);
  }

  // ---- output projection ----
  transpose_w<<<dim3(VTOK / 64, DM / 64, 1), 256, 0, stream>>>(out_w, WT, DM, VTOK);
  launch_gemm<128, 0, 0, 0>(stream, dcur_bf, WT, out_b, out,
                            M, VTOK, DM, DM, DM, VTOK, 0, 0, 0, 0, 0, 0, 1.0f, 1);
}

// Round 3
// 1699.709 us; speedup vs baseline: 8.4888x; 1.6980x over previous
//
#include <hip/hip_runtime.h>
#include <hip/hip_bf16.h>
#include <math.h>

#define NSL 4
#define DM 1024
#define NH 16
#define DKH 64
#define DFF 4096
#define BB 2
#define LL 512
#define VTOK 32000

typedef short s16x8 __attribute__((ext_vector_type(8)));
typedef float f32x4 __attribute__((ext_vector_type(4)));

__device__ __forceinline__ void gload16(const void* g, void* l) {
  __builtin_amdgcn_global_load_lds((__attribute__((address_space(1))) void*)g,
                                   (__attribute__((address_space(3))) void*)l, 16, 0, 0);
}

// ---------------------------------------------------------------- embedding (fp32 + bf16 out)
__global__ __launch_bounds__(256) void embed_kernel(
    const int* __restrict__ tok, const float* __restrict__ w,
    float* __restrict__ o, __hip_bfloat16* __restrict__ obf) {
  const int idx = blockIdx.x * 256 + threadIdx.x;   // BB*LL*DM
  const int dim = idx & (DM - 1);
  const int pos = (idx >> 10) & (LL - 1);
  const int b   = idx >> 19;
  const int token = tok[b * LL + pos];
  const float denum = powf(10000.0f, (2.0f * (float)dim) / (float)DM);
  const float pe = (float)pos / denum;
  const float val = (dim & 1) ? cosf(pe) : (1.0f + sinf(pe));
  const float r = w[(size_t)token * DM + dim] + val;
  o[idx] = r;
  obf[idx] = __float2bfloat16(r);
}

// ---------------------------------------------------------------- weight transpose fp32[K][N] -> bf16[N][K]
__global__ __launch_bounds__(256) void transpose_w(
    const float* __restrict__ W, __hip_bfloat16* __restrict__ WT, int K, int N) {
  __shared__ float t[64][65];
  const long mat = blockIdx.z;
  const float* src = W + mat * (long)K * N;
  __hip_bfloat16* dst = WT + mat * (long)N * K;
  const int n0 = blockIdx.x * 64, k0 = blockIdx.y * 64;
  const int lc = (threadIdx.x & 15) * 4;
  const int lr = threadIdx.x >> 4;
  #pragma unroll
  for (int u = 0; u < 4; ++u) {
    const int r = lr + u * 16;
    const float4 v = *(const float4*)(src + (long)(k0 + r) * N + n0 + lc);
    t[r][lc + 0] = v.x; t[r][lc + 1] = v.y; t[r][lc + 2] = v.z; t[r][lc + 3] = v.w;
  }
  __syncthreads();
  #pragma unroll
  for (int u = 0; u < 4; ++u) {
    const int r = lr + u * 16;     // n index
    ushort4 o;
    __hip_bfloat16 h0 = __float2bfloat16(t[lc + 0][r]);
    __hip_bfloat16 h1 = __float2bfloat16(t[lc + 1][r]);
    __hip_bfloat16 h2 = __float2bfloat16(t[lc + 2][r]);
    __hip_bfloat16 h3 = __float2bfloat16(t[lc + 3][r]);
    o.x = *(unsigned short*)&h0; o.y = *(unsigned short*)&h1;
    o.z = *(unsigned short*)&h2; o.w = *(unsigned short*)&h3;
    *(ushort4*)(dst + (long)(n0 + r) * K + k0 + lc) = o;
  }
}

// ---------------------------------------------------------------- V transpose bf16 [B*LL][ldv] slice -> VT[B][DM][LL]
__global__ __launch_bounds__(256) void transpose_v(
    const __hip_bfloat16* __restrict__ V, __hip_bfloat16* __restrict__ VT, int ldv) {
  __shared__ __hip_bfloat16 t[64][65];
  const int b = blockIdx.z;
  const int j0 = blockIdx.x * 64, d0 = blockIdx.y * 64;
  const int tx = threadIdx.x & 63, ty = threadIdx.x >> 6;
  const __hip_bfloat16* src = V + (long)b * LL * ldv;
  __hip_bfloat16* dst = VT + (long)b * DM * LL;
  #pragma unroll
  for (int u = 0; u < 16; ++u) {
    const int r = ty * 16 + u;                 // j
    t[r][tx] = src[(long)(j0 + r) * ldv + d0 + tx];
  }
  __syncthreads();
  #pragma unroll
  for (int u = 0; u < 16; ++u) {
    const int r = ty * 16 + u;                 // d
    dst[(long)(d0 + r) * LL + j0 + tx] = t[tx][r];
  }
}

// ---------------------------------------------------------------- MFMA GEMM
// C[M,N] = A[M,K] @ BT[N,K]^T + bias ; A,BT bf16 k-contiguous
template<int BM, int BN, int RELU, int OBF, int SWZ>
__global__ __launch_bounds__(256) void gemm_mfma(
    const __hip_bfloat16* __restrict__ A, const __hip_bfloat16* __restrict__ BT,
    const float* __restrict__ bias, void* __restrict__ Cout,
    int K, int lda, int ldb, int ldc) {
  constexpr int BK = 32;
  constexpr int WR = BM / 2, WC = BN / 2;
  constexpr int MF = WR / 16, NF = WC / 16;
  constexpr int ACALLS = BM / 64, BCALLS = BN / 64;
  __shared__ __align__(16) __hip_bfloat16 As[BM * BK];
  __shared__ __align__(16) __hip_bfloat16 Bs[BN * BK];
  int bx = blockIdx.x, by = blockIdx.y;
  if (SWZ) {
    const int gx = gridDim.x;
    const int nwg = gx * gridDim.y;     // must be %8 == 0 (caller guarantees)
    const int id = by * gx + bx;
    const int qq = nwg >> 3;
    const int swz = (id & 7) * qq + (id >> 3);
    bx = swz % gx; by = swz / gx;
  }
  const int bm = by * BM, bn = bx * BN;
  const int tid = threadIdx.x, lane = tid & 63, wid = tid >> 6;
  const int wr = (wid >> 1) * WR, wc = (wid & 1) * WC;
  const int l_row = lane >> 2, l_chk = lane & 3;
  const int frow = lane & 15, fkc = lane >> 4;
  f32x4 acc[MF][NF] = {};
  for (int k0 = 0; k0 < K; k0 += BK) {
    #pragma unroll
    for (int c = 0; c < ACALLS; ++c) {
      const int R0 = (wid * ACALLS + c) * 16;
      const int row = R0 + l_row;
      const int chk = l_chk ^ ((row >> 1) & 3);   // pre-swizzled source (rule #21)
      gload16(A + (long)(bm + row) * lda + k0 + chk * 8, &As[R0 * BK]);
    }
    #pragma unroll
    for (int c = 0; c < BCALLS; ++c) {
      const int R0 = (wid * BCALLS + c) * 16;
      const int row = R0 + l_row;
      const int chk = l_chk ^ ((row >> 1) & 3);
      gload16(BT + (long)(bn + row) * ldb + k0 + chk * 8, &Bs[R0 * BK]);
    }
    __syncthreads();
    s16x8 af[MF], bfr[NF];
    #pragma unroll
    for (int mm = 0; mm < MF; ++mm) {
      const int r = wr + mm * 16 + frow;
      af[mm] = *(const s16x8*)&As[r * BK + ((fkc ^ ((r >> 1) & 3)) * 8)];
    }
    #pragma unroll
    for (int nn = 0; nn < NF; ++nn) {
      const int r = wc + nn * 16 + frow;
      bfr[nn] = *(const s16x8*)&Bs[r * BK + ((fkc ^ ((r >> 1) & 3)) * 8)];
    }
    #pragma unroll
    for (int mm = 0; mm < MF; ++mm)
      #pragma unroll
      for (int nn = 0; nn < NF; ++nn)
        acc[mm][nn] = __builtin_amdgcn_mfma_f32_16x16x32_bf16(af[mm], bfr[nn], acc[mm][nn], 0, 0, 0);
    __syncthreads();
  }
  #pragma unroll
  for (int mm = 0; mm < MF; ++mm)
    #pragma unroll
    for (int nn = 0; nn < NF; ++nn)
      #pragma unroll
      for (int j = 0; j < 4; ++j) {
        const int row = bm + wr + mm * 16 + fkc * 4 + j;
        const int col = bn + wc + nn * 16 + frow;
        float v = acc[mm][nn][j] + bias[col];
        if (RELU) v = fmaxf(v, 0.0f);
        const long ci = (long)row * ldc + col;
        if (OBF) ((__hip_bfloat16*)Cout)[ci] = __float2bfloat16(v);
        else     ((float*)Cout)[ci] = v;
      }
}

// ---------------------------------------------------------------- flash attention
// grid: (LL/64 q-tiles, BB*NH). 4 waves, each 16 q-rows. D=64.
// Q[row][ldq] (head offset h*64), K[row][ldk], VT[b][DM][LL] (j-contiguous), O = ab_bf [B*LL][DM].
template<int CAUSAL>
__global__ __launch_bounds__(256) void flash_attn(
    const __hip_bfloat16* __restrict__ Q, int ldq,
    const __hip_bfloat16* __restrict__ K, int ldk,
    const __hip_bfloat16* __restrict__ VT,
    __hip_bfloat16* __restrict__ O) {
  __shared__ __align__(16) __hip_bfloat16 Ks[64 * 64];
  __shared__ __align__(16) __hip_bfloat16 Vs[64 * 64];
  __shared__ __align__(16) __hip_bfloat16 Ps[4][16 * 64];
  const int qt = blockIdx.x;
  const int bh = blockIdx.y;
  const int b = bh >> 4, h = bh & (NH - 1);
  const int tid = threadIdx.x, lane = tid & 63, wid = tid >> 6;
  const int frow = lane & 15, fg = lane >> 4;

  const __hip_bfloat16* Qb = Q + ((long)b * LL) * ldq + h * DKH;
  const __hip_bfloat16* Kb = K + ((long)b * LL) * ldk + h * DKH;
  const __hip_bfloat16* Vb = VT + (long)b * DM * LL + (long)(h * DKH) * LL;
  __hip_bfloat16* Ob = O + ((long)b * LL) * DM + h * DKH;

  // Q fragments: A-layout row = lane&15, k-chunk = lane>>4
  const int qrow = qt * 64 + wid * 16 + frow;
  s16x8 aq[2];
  #pragma unroll
  for (int s = 0; s < 2; ++s)
    aq[s] = *(const s16x8*)(Qb + (long)qrow * ldq + s * 32 + fg * 8);

  f32x4 o[4] = {};
  float m[4], l[4];
  #pragma unroll
  for (int j = 0; j < 4; ++j) { m[j] = -INFINITY; l[j] = 0.0f; }

  const int ntiles = CAUSAL ? (qt + 1) : (LL / 64);
  for (int jt = 0; jt < ntiles; ++jt) {
    // stage K-tile [64 j][64 d] and V^T-tile [64 d][64 j], XOR chunk swizzle via source
    #pragma unroll
    for (int u = 0; u < 2; ++u) {
      const int R0 = (wid * 2 + u) * 8;
      const int row = R0 + (lane >> 3);
      const int cg = (lane & 7) ^ (row & 7);
      gload16(Kb + (long)(jt * 64 + row) * ldk + cg * 8, &Ks[R0 * 64]);
      gload16(Vb + (long)row * LL + jt * 64 + cg * 8, &Vs[R0 * 64]);
    }
    __syncthreads();

    // S = (Q K^T) * 0.125
    f32x4 sa[4] = {};
    #pragma unroll
    for (int s = 0; s < 2; ++s)
      #pragma unroll
      for (int nf = 0; nf < 4; ++nf) {
        const int jr = nf * 16 + frow;
        const s16x8 kf = *(const s16x8*)&Ks[jr * 64 + (((s * 4 + fg) ^ (jr & 7)) * 8)];
        sa[nf] = __builtin_amdgcn_mfma_f32_16x16x32_bf16(aq[s], kf, sa[nf], 0, 0, 0);
      }
    #pragma unroll
    for (int nf = 0; nf < 4; ++nf)
      #pragma unroll
      for (int j = 0; j < 4; ++j) {
        float v = sa[nf][j] * 0.125f;
        if (CAUSAL) {
          const int r = qt * 64 + wid * 16 + fg * 4 + j;
          const int c = jt * 64 + nf * 16 + frow;
          if (c > r) v = -1e30f;
        }
        sa[nf][j] = v;
      }

    // online softmax: row max (in-lane over nf, xor-reduce over j-col lanes)
    float fs[4];
    #pragma unroll
    for (int j = 0; j < 4; ++j) {
      float v = fmaxf(fmaxf(sa[0][j], sa[1][j]), fmaxf(sa[2][j], sa[3][j]));
      v = fmaxf(v, __shfl_xor(v, 1));
      v = fmaxf(v, __shfl_xor(v, 2));
      v = fmaxf(v, __shfl_xor(v, 4));
      v = fmaxf(v, __shfl_xor(v, 8));
      const float mn = fmaxf(m[j], v);
      fs[j] = __expf(m[j] - mn);
      m[j] = mn;
    }
    float rs[4] = {0.0f, 0.0f, 0.0f, 0.0f};
    #pragma unroll
    for (int nf = 0; nf < 4; ++nf)
      #pragma unroll
      for (int j = 0; j < 4; ++j) {
        const float p = __expf(sa[nf][j] - m[j]);
        sa[nf][j] = p;
        rs[j] += p;
      }
    #pragma unroll
    for (int j = 0; j < 4; ++j) {
      float v = rs[j];
      v += __shfl_xor(v, 1);
      v += __shfl_xor(v, 2);
      v += __shfl_xor(v, 4);
      v += __shfl_xor(v, 8);
      l[j] = l[j] * fs[j] + v;
      o[0][j] *= fs[j]; o[1][j] *= fs[j]; o[2][j] *= fs[j]; o[3][j] *= fs[j];
    }

    // P (C-layout) -> wave-private LDS (A-layout source), XOR-swizzled
    __hip_bfloat16* Pw = &Ps[wid][0];
    #pragma unroll
    for (int nf = 0; nf < 4; ++nf)
      #pragma unroll
      for (int j = 0; j < 4; ++j) {
        const int qr = fg * 4 + j;
        const int col = nf * 16 + frow;
        Pw[qr * 64 + (((col >> 3) ^ (qr & 7)) * 8) + (col & 7)] = __float2bfloat16(sa[nf][j]);
      }
    asm volatile("s_waitcnt lgkmcnt(0)" ::: "memory");

    // O += P V
    #pragma unroll
    for (int s = 0; s < 2; ++s) {
      const s16x8 pa = *(const s16x8*)&Pw[frow * 64 + (((s * 4 + fg) ^ (frow & 7)) * 8)];
      #pragma unroll
      for (int nf = 0; nf < 4; ++nf) {
        const int dr = nf * 16 + frow;
        const s16x8 vf = *(const s16x8*)&Vs[dr * 64 + (((s * 4 + fg) ^ (dr & 7)) * 8)];
        o[nf] = __builtin_amdgcn_mfma_f32_16x16x32_bf16(pa, vf, o[nf], 0, 0, 0);
      }
    }
    __syncthreads();
  }

  #pragma unroll
  for (int nf = 0; nf < 4; ++nf)
    #pragma unroll
    for (int j = 0; j < 4; ++j) {
      const int row = qt * 64 + wid * 16 + fg * 4 + j;
      const int col = nf * 16 + frow;
      Ob[(long)row * DM + col] = __float2bfloat16(o[nf][j] / l[j]);
    }
}

// ---------------------------------------------------------------- add + LN (fp32 + bf16 out)
__global__ __launch_bounds__(256) void add_ln(
    const float* __restrict__ x, const float* __restrict__ r,
    const float* __restrict__ g, const float* __restrict__ bta,
    float* __restrict__ out, __hip_bfloat16* __restrict__ obf) {
  __shared__ float red[256];
  const int tid = threadIdx.x;
  const size_t base = (size_t)blockIdx.x * DM;
  float v[4];
  #pragma unroll
  for (int u = 0; u < 4; ++u) {
    const int c = tid + u * 256;
    v[u] = x[base + c] + r[base + c];
  }
  red[tid] = v[0] + v[1] + v[2] + v[3];
  __syncthreads();
  for (int s = 128; s > 0; s >>= 1) {
    if (tid < s) red[tid] += red[tid + s];
    __syncthreads();
  }
  const float mean = red[0] * (1.0f / DM);
  __syncthreads();
  float sq = 0.0f;
  #pragma unroll
  for (int u = 0; u < 4; ++u) { const float d = v[u] - mean; sq += d * d; }
  red[tid] = sq;
  __syncthreads();
  for (int s = 128; s > 0; s >>= 1) {
    if (tid < s) red[tid] += red[tid + s];
    __syncthreads();
  }
  const float rstd = rsqrtf(red[0] * (1.0f / DM) + 1e-5f);
  #pragma unroll
  for (int u = 0; u < 4; ++u) {
    const int c = tid + u * 256;
    const float o = g[c] * (v[u] - mean) * rstd + bta[c];
    out[base + c] = o;
    obf[base + c] = __float2bfloat16(o);
  }
}

__global__ __launch_bounds__(256) void addvec(
    const float* __restrict__ a, const float* __restrict__ b,
    float* __restrict__ o, __hip_bfloat16* __restrict__ obf) {
  const int i = blockIdx.x * 256 + threadIdx.x;
  const float r = a[i] + b[i];
  o[i] = r;
  obf[i] = __float2bfloat16(r);
}

// ---------------------------------------------------------------- host helpers
template<int BM, int BN, int RELU, int OBF, int SWZ>
static inline void launch_gemm(hipStream_t st, const __hip_bfloat16* A, const __hip_bfloat16* BT,
                               const float* bias, void* C, int M, int N, int K,
                               int lda, int ldb, int ldc) {
  dim3 g(N / BN, M / BM);
  gemm_mfma<BM, BN, RELU, OBF, SWZ><<<g, 256, 0, st>>>(A, BT, bias, C, K, lda, ldb, ldc);
}

static inline void attention(hipStream_t st,
                             const __hip_bfloat16* q, int ldq,
                             const __hip_bfloat16* k, int ldk,
                             const __hip_bfloat16* v, int ldv,
                             __hip_bfloat16* VT, __hip_bfloat16* ab, bool causal) {
  transpose_v<<<dim3(LL / 64, DM / 64, BB), 256, 0, st>>>(v, VT, ldv);
  if (causal) flash_attn<1><<<dim3(LL / 64, BB * NH), 256, 0, st>>>(q, ldq, k, ldk, VT, ab);
  else        flash_attn<0><<<dim3(LL / 64, BB * NH), 256, 0, st>>>(q, ldq, k, ldk, VT, ab);
}

extern "C" void kernel_launch(void* const* d_in, const int* in_sizes, int n_in,
                              void* d_out, int out_size, void* d_ws, size_t ws_size,
                              hipStream_t stream) {
  (void)in_sizes; (void)n_in; (void)out_size; (void)ws_size;
  const int*   s          = (const int*)d_in[0];
  const int*   t          = (const int*)d_in[1];
  const float* emb_s_w    = (const float*)d_in[2];
  const float* emb_t_w    = (const float*)d_in[3];
  const float* enc_qkv_w  = (const float*)d_in[4];
  const float* enc_qkv_b  = (const float*)d_in[5];
  const float* enc_o_w    = (const float*)d_in[6];
  const float* enc_o_b    = (const float*)d_in[7];
  const float* enc_ln_w   = (const float*)d_in[8];
  const float* enc_ln_b   = (const float*)d_in[9];
  const float* enc_w1     = (const float*)d_in[10];
  const float* enc_b1     = (const float*)d_in[11];
  const float* enc_w2     = (const float*)d_in[12];
  const float* enc_b2     = (const float*)d_in[13];
  const float* dec_qkv1_w = (const float*)d_in[14];
  const float* dec_qkv1_b = (const float*)d_in[15];
  const float* dec_o1_w   = (const float*)d_in[16];
  const float* dec_o1_b   = (const float*)d_in[17];
  const float* dec_qkv2_w = (const float*)d_in[18];
  const float* dec_qkv2_b = (const float*)d_in[19];
  const float* dec_o2_w   = (const float*)d_in[20];
  const float* dec_o2_b   = (const float*)d_in[21];
  const float* dec_ln_w   = (const float*)d_in[22];
  const float* dec_ln_b   = (const float*)d_in[23];
  const float* dec_w1     = (const float*)d_in[24];
  const float* dec_b1     = (const float*)d_in[25];
  const float* dec_w2     = (const float*)d_in[26];
  const float* dec_b2     = (const float*)d_in[27];
  const float* out_w      = (const float*)d_in[28];
  const float* out_b      = (const float*)d_in[29];
  float* out = (float*)d_out;

  char* p = (char*)d_ws;
  auto alloc = [&](size_t bytes) {
    char* r = p; p += (bytes + 255) & ~(size_t)255; return (void*)r;
  };
  const size_t T = (size_t)BB * LL * DM;
  float* e    = (float*)alloc(T * 4);
  float* dcur = (float*)alloc(T * 4);
  float* tmp  = (float*)alloc(T * 4);
  float* d1b  = (float*)alloc(T * 4);
  float* d2b  = (float*)alloc(T * 4);
  __hip_bfloat16* e_bf    = (__hip_bfloat16*)alloc(T * 2);
  __hip_bfloat16* dcur_bf = (__hip_bfloat16*)alloc(T * 2);
  __hip_bfloat16* d1b_bf  = (__hip_bfloat16*)alloc(T * 2);
  __hip_bfloat16* d2b_bf  = (__hip_bfloat16*)alloc(T * 2);
  __hip_bfloat16* q_bf    = (__hip_bfloat16*)alloc(T * 2);
  __hip_bfloat16* qkv_bf  = (__hip_bfloat16*)alloc((size_t)BB * LL * 3 * DM * 2);
  __hip_bfloat16* ab_bf   = (__hip_bfloat16*)alloc(T * 2);
  __hip_bfloat16* hid_bf  = (__hip_bfloat16*)alloc((size_t)BB * LL * DFF * 2);
  __hip_bfloat16* VT      = (__hip_bfloat16*)alloc((size_t)BB * DM * LL * 2);
  __hip_bfloat16* WT      = (__hip_bfloat16*)alloc((size_t)VTOK * DM * 2);

  const int M = BB * LL;

  embed_kernel<<<(int)(T / 256), 256, 0, stream>>>(s, emb_s_w, e, e_bf);
  embed_kernel<<<(int)(T / 256), 256, 0, stream>>>(t, emb_t_w, dcur, dcur_bf);

  // ---- encoder ----
  for (int i = 0; i < NSL; ++i) {
    transpose_w<<<dim3(DM / 64, DM / 64, 3), 256, 0, stream>>>(
        enc_qkv_w + (size_t)i * 3 * DM * DM, WT, DM, DM);
    launch_gemm<64, 64, 0, 1, 0>(stream, e_bf, WT, enc_qkv_b + (size_t)i * 3 * DM, qkv_bf,
                                 M, 3 * DM, DM, DM, DM, 3 * DM);
    attention(stream, qkv_bf, 3 * DM, qkv_bf + DM, 3 * DM, qkv_bf + 2 * DM, 3 * DM,
              VT, ab_bf, false);
    transpose_w<<<dim3(DM / 64, DM / 64, 1), 256, 0, stream>>>(
        enc_o_w + (size_t)i * DM * DM, WT, DM, DM);
    launch_gemm<64, 64, 0, 0, 0>(stream, ab_bf, WT, enc_o_b + (size_t)i * DM, tmp,
                                 M, DM, DM, DM, DM, DM);
    add_ln<<<M, 256, 0, stream>>>(tmp, e, enc_ln_w + (size_t)i * DM, enc_ln_b + (size_t)i * DM, e, e_bf);
    transpose_w<<<dim3(DFF / 64, DM / 64, 1), 256, 0, stream>>>(
        enc_w1 + (size_t)i * DM * DFF, WT, DM, DFF);
    launch_gemm<128, 128, 1, 1, 0>(stream, e_bf, WT, enc_b1 + (size_t)i * DFF, hid_bf,
                                   M, DFF, DM, DM, DM, DFF);
    transpose_w<<<dim3(DM / 64, DFF / 64, 1), 256, 0, stream>>>(
        enc_w2 + (size_t)i * DFF * DM, WT, DFF, DM);
    launch_gemm<64, 64, 0, 0, 0>(stream, hid_bf, WT, enc_b2 + (size_t)i * DM, tmp,
                                 M, DM, DFF, DFF, DFF, DM);
    add_ln<<<M, 256, 0, stream>>>(tmp, e, enc_ln_w + (size_t)i * DM, enc_ln_b + (size_t)i * DM, e, e_bf);
  }

  // ---- decoder ----
  for (int i = 0; i < NSL; ++i) {
    transpose_w<<<dim3(DM / 64, DM / 64, 3), 256, 0, stream>>>(
        dec_qkv1_w + (size_t)i * 3 * DM * DM, WT, DM, DM);
    launch_gemm<64, 64, 0, 1, 0>(stream, dcur_bf, WT, dec_qkv1_b + (size_t)i * 3 * DM, qkv_bf,
                                 M, 3 * DM, DM, DM, DM, 3 * DM);
    attention(stream, qkv_bf, 3 * DM, qkv_bf + DM, 3 * DM, qkv_bf + 2 * DM, 3 * DM,
              VT, ab_bf, true);
    transpose_w<<<dim3(DM / 64, DM / 64, 1), 256, 0, stream>>>(
        dec_o1_w + (size_t)i * DM * DM, WT, DM, DM);
    launch_gemm<64, 64, 0, 0, 0>(stream, ab_bf, WT, dec_o1_b + (size_t)i * DM, tmp,
                                 M, DM, DM, DM, DM, DM);
    add_ln<<<M, 256, 0, stream>>>(tmp, dcur, dec_ln_w + (size_t)i * DM, dec_ln_b + (size_t)i * DM, d1b, d1b_bf);

    transpose_w<<<dim3(DM / 64, DM / 64, 3), 256, 0, stream>>>(
        dec_qkv2_w + (size_t)i * 3 * DM * DM, WT, DM, DM);
    launch_gemm<64, 64, 0, 1, 0>(stream, d1b_bf, WT, dec_qkv2_b + (size_t)i * 3 * DM, q_bf,
                                 M, DM, DM, DM, DM, DM);
    launch_gemm<64, 64, 0, 1, 0>(stream, e_bf, WT + (size_t)DM * DM,
                                 dec_qkv2_b + (size_t)i * 3 * DM + DM, qkv_bf,
                                 M, 2 * DM, DM, DM, DM, 2 * DM);
    attention(stream, q_bf, DM, qkv_bf, 2 * DM, qkv_bf + DM, 2 * DM,
              VT, ab_bf, true);   // causal cross-attn (faithful quirk)
    transpose_w<<<dim3(DM / 64, DM / 64, 1), 256, 0, stream>>>(
        dec_o2_w + (size_t)i * DM * DM, WT, DM, DM);
    launch_gemm<64, 64, 0, 0, 0>(stream, ab_bf, WT, dec_o2_b + (size_t)i * DM, tmp,
                                 M, DM, DM, DM, DM, DM);
    add_ln<<<M, 256, 0, stream>>>(tmp, d1b, dec_ln_w + (size_t)i * DM, dec_ln_b + (size_t)i * DM, d2b, d2b_bf);

    transpose_w<<<dim3(DFF / 64, DM / 64, 1), 256, 0, stream>>>(
        dec_w1 + (size_t)i * DM * DFF, WT, DM, DFF);
    launch_gemm<128, 128, 1, 1, 0>(stream, d2b_bf, WT, dec_b1 + (size_t)i * DFF, hid_bf,
                                   M, DFF, DM, DM, DM, DFF);
    transpose_w<<<dim3(DM / 64, DFF / 64, 1), 256, 0, stream>>>(
        dec_w2 + (size_t)i * DFF * DM, WT, DFF, DM);
    launch_gemm<64, 64, 0, 0, 0>(stream, hid_bf, WT, dec_b2 + (size_t)i * DM, tmp,
                                 M, DM, DFF, DFF, DFF, DM);
    addvec<<<(int)(T / 256), 256, 0, stream>>>(tmp, d2b, dcur, dcur_bf);
  }

  // ---- output projection ----
  transpose_w<<<dim3(VTOK / 64, DM / 64, 1), 256, 0, stream>>>(out_w, WT, DM, VTOK);
  launch_gemm<128, 128, 0, 0, 1>(stream, dcur_bf, WT, out_b, out,
                                 M, VTOK, DM, DM, DM, VTOK);
}